// Round 1
// baseline (685.728 us; speedup 1.0000x reference)
//
#include <hip/hip_runtime.h>
#include <hip/hip_bf16.h>

// ---------------------------------------------------------------------------
// MoE layer: router (softmax, top-2) + 16 experts (D=2048 -> H=1024 -> D) +
// shared expert (D -> F=1024 -> D), gate-weighted combine, aux stats.
// Strategy: top-2 sparse dispatch + bf16 MFMA GEMMs (m97-style 128x128 tile,
// global_load_lds width 16, k-slot XOR swizzle for conflict-light ds_read_b128).
// ---------------------------------------------------------------------------

#define N_TOK 8192
#define DDIM  2048
#define NEXP  16
#define HDIM  1024
#define FDIM  1024
#define NASSIGN (N_TOK * 2)

typedef __attribute__((ext_vector_type(8))) short bf16x8;
typedef __attribute__((ext_vector_type(4))) float f32x4;
typedef __attribute__((ext_vector_type(8))) unsigned short u16x8;
typedef __attribute__((ext_vector_type(4))) unsigned short u16x4;

__device__ inline unsigned short f2bf(float f) {
    unsigned int u = __builtin_bit_cast(unsigned int, f);
    u += 0x7FFFu + ((u >> 16) & 1u);           // RNE (finite inputs only)
    return (unsigned short)(u >> 16);
}

__device__ inline float gelu_f(float v) {
    return 0.5f * v * (1.0f + erff(v * 0.7071067811865475f));
}

__device__ inline void gld16(void* lds, const void* g) {
    __builtin_amdgcn_global_load_lds(
        (const __attribute__((address_space(1))) unsigned int*)g,
        (__attribute__((address_space(3))) unsigned int*)lds, 16, 0, 0);
}

// ---------------------------------------------------------------------------
__global__ __launch_bounds__(256) void zero_small(float* imp) {
    if (threadIdx.x < NEXP) imp[threadIdx.x] = 0.0f;
}

// x fp32 -> bf16, 8 elems/thread
__global__ __launch_bounds__(256) void cast_x_kernel(const float* __restrict__ x,
                                                     unsigned short* __restrict__ xb) {
    size_t i = (size_t)blockIdx.x * 256 + threadIdx.x;   // group of 8
    const float4 a = ((const float4*)x)[i * 2];
    const float4 b = ((const float4*)x)[i * 2 + 1];
    u16x8 o;
    o[0] = f2bf(a.x); o[1] = f2bf(a.y); o[2] = f2bf(a.z); o[3] = f2bf(a.w);
    o[4] = f2bf(b.x); o[5] = f2bf(b.y); o[6] = f2bf(b.z); o[7] = f2bf(b.w);
    *(u16x8*)(xb + i * 8) = o;
}

// [R][C] fp32 -> [C][R] bf16, 64x64 LDS tiles, batched over blockIdx.z
template <int R, int C>
__global__ __launch_bounds__(256) void transpose_cast(const float* __restrict__ src,
                                                      unsigned short* __restrict__ dst) {
    __shared__ unsigned short t[64][66];
    const size_t zoff = (size_t)blockIdx.z * R * C;
    src += zoff; dst += zoff;
    const int r0 = blockIdx.y * 64, c0 = blockIdx.x * 64;
    const int tid = threadIdx.x;
    const int cr = tid >> 4;            // 0..15
    const int cc4 = (tid & 15) * 4;
#pragma unroll
    for (int it = 0; it < 4; ++it) {
        int row = cr + it * 16;
        const float4 v = *(const float4*)(src + (size_t)(r0 + row) * C + c0 + cc4);
        t[row][cc4 + 0] = f2bf(v.x); t[row][cc4 + 1] = f2bf(v.y);
        t[row][cc4 + 2] = f2bf(v.z); t[row][cc4 + 3] = f2bf(v.w);
    }
    __syncthreads();
#pragma unroll
    for (int it = 0; it < 4; ++it) {
        int cc = cr + it * 16;
        u16x4 o;
#pragma unroll
        for (int j = 0; j < 4; ++j) o[j] = t[cc4 + j][cc];
        *(u16x4*)(dst + (size_t)(c0 + cc) * R + r0 + cc4) = o;
    }
}

// ---------------------------------------------------------------------------
// Router: one wave per token. logits = x@Wr (16), gate = x@Wg; softmax; top-2.
__global__ __launch_bounds__(256) void router_kernel(
    const float* __restrict__ x, const float* __restrict__ Wr, const float* __restrict__ Wg,
    float* __restrict__ gsh, int* __restrict__ t2i, float* __restrict__ t2v,
    float* __restrict__ imp) {
    __shared__ float simp[NEXP];
    const int tid = threadIdx.x, lane = tid & 63, w = tid >> 6;
    if (tid < NEXP) simp[tid] = 0.0f;
    __syncthreads();
    const int n = blockIdx.x * 4 + w;
    const float* xr = x + (size_t)n * DDIM;
    float acc[NEXP];
#pragma unroll
    for (int e = 0; e < NEXP; ++e) acc[e] = 0.0f;
    float ag = 0.0f;
    for (int j = 0; j < DDIM / 64; ++j) {
        int d = lane + j * 64;
        float xv = xr[d];
        const float* wr = Wr + (size_t)d * NEXP;
#pragma unroll
        for (int e = 0; e < NEXP; ++e) acc[e] = fmaf(xv, wr[e], acc[e]);
        ag = fmaf(xv, Wg[d], ag);
    }
#pragma unroll
    for (int off = 32; off; off >>= 1) {
#pragma unroll
        for (int e = 0; e < NEXP; ++e) acc[e] += __shfl_xor(acc[e], off);
        ag += __shfl_xor(ag, off);
    }
    if (lane == 0) {
        float mx = acc[0];
#pragma unroll
        for (int e = 1; e < NEXP; ++e) mx = fmaxf(mx, acc[e]);
        float p[NEXP], s = 0.0f;
#pragma unroll
        for (int e = 0; e < NEXP; ++e) { p[e] = expf(acc[e] - mx); s += p[e]; }
        const float inv = 1.0f / s;
        int i1 = 0; float v1 = -1.0f;
#pragma unroll
        for (int e = 0; e < NEXP; ++e) {
            p[e] *= inv;
            if (p[e] > v1) { v1 = p[e]; i1 = e; }
        }
        int i2 = 0; float v2 = -1.0f;
#pragma unroll
        for (int e = 0; e < NEXP; ++e) {
            if (e != i1 && p[e] > v2) { v2 = p[e]; i2 = e; }
        }
        t2i[2 * n] = i1; t2i[2 * n + 1] = i2;
        t2v[2 * n] = v1; t2v[2 * n + 1] = v2;
        gsh[n] = 1.0f / (1.0f + expf(-ag));
#pragma unroll
        for (int e = 0; e < NEXP; ++e) atomicAdd(&simp[e], p[e]);
    }
    __syncthreads();
    if (tid < NEXP) unsafeAtomicAdd(&imp[tid], simp[tid]);
}

// Single block: histogram counts, exclusive scan -> offsets, aux outputs, fill=0
__global__ __launch_bounds__(256) void scan_finalize(
    const int* __restrict__ t2i, const float* __restrict__ imp,
    int* __restrict__ offs, int* __restrict__ fill, float* __restrict__ out_tail) {
    __shared__ int hist[NEXP];
    const int tid = threadIdx.x;
    if (tid < NEXP) hist[tid] = 0;
    __syncthreads();
    for (int i = tid; i < NASSIGN; i += 256) atomicAdd(&hist[t2i[i]], 1);
    __syncthreads();
    if (tid == 0) {
        int o = 0;
        for (int e = 0; e < NEXP; ++e) { offs[e] = o; o += hist[e]; }
        offs[NEXP] = o;
    }
    if (tid < NEXP) {
        fill[tid] = 0;
        out_tail[tid] = imp[tid] * (1.0f / (float)N_TOK);
        out_tail[NEXP + tid] = (float)hist[tid] / (float)NASSIGN;
    }
}

__global__ __launch_bounds__(256) void build_assign(
    const int* __restrict__ t2i, const float* __restrict__ t2v,
    const int* __restrict__ offs, int* __restrict__ fill,
    int* __restrict__ atok, float* __restrict__ agate) {
    const int n = blockIdx.x * 256 + threadIdx.x;
#pragma unroll
    for (int k = 0; k < 2; ++k) {
        int e = t2i[2 * n + k];
        int pos = offs[e] + atomicAdd(&fill[e], 1);
        atok[pos] = n;
        agate[pos] = t2v[2 * n + k];
    }
}

// ---------------------------------------------------------------------------
// GEMM: C[M][NC] = A[M][KD] * B^T[NC][KD]   (both bf16, fp32 accum)
// MODE 0: expert L1  (A = gathered x, out = gelu*gate -> Hb)
// MODE 1: expert L2  (A = Hb, out = atomicAdd into Y[token])
// MODE 2: shared L1  (A = x, out = gelu -> Hb)
// MODE 3: shared L2  (A = Hs, out = Y[row] = gsh*acc, plain store)
template <int MODE>
__global__ __launch_bounds__(256) void gemm_tile(
    const unsigned short* __restrict__ A, const unsigned short* __restrict__ B,
    float* __restrict__ Y, unsigned short* __restrict__ Hb,
    const int* __restrict__ offs, const int* __restrict__ atok,
    const float* __restrict__ agate, const float* __restrict__ gsh) {
    constexpr int KD = (MODE == 0 || MODE == 2) ? DDIM : HDIM;
    constexpr int NC = (MODE == 0 || MODE == 2) ? HDIM : DDIM;
    const int e = blockIdx.z;
    int m0 = 0, mE = N_TOK;
    if (MODE <= 1) { m0 = offs[e]; mE = offs[e + 1] - m0; }
    const int tm = blockIdx.y;
    if (tm * 128 >= mE) return;
    const int n0 = blockIdx.x * 128;

    __shared__ __align__(16) unsigned short As[128 * 32];
    __shared__ __align__(16) unsigned short Bs[128 * 32];

    const int tid = threadIdx.x, lane = tid & 63;
    const int wid = tid >> 6, wm = wid >> 1, wn = wid & 1;

    // staging descriptors: 2 chunks of A + 2 of B per thread per K-step
    const unsigned short* srcA[2];
    const unsigned short* srcB[2];
    char* dstA[2];
    char* dstB[2];
#pragma unroll
    for (int it = 0; it < 2; ++it) {
        int c = tid + it * 256;
        int row = c >> 2, slot = c & 3;
        int ksw = (slot ^ ((row >> 1) & 3)) * 8;   // pre-swizzled global k-chunk
        int arow = tm * 128 + row;
        if (MODE == 0) {
            int ar = arow < mE ? arow : mE - 1;
            srcA[it] = A + (size_t)atok[m0 + ar] * DDIM + ksw;
        } else if (MODE == 1) {
            int ar = arow < mE ? arow : mE - 1;
            srcA[it] = A + (size_t)(m0 + ar) * HDIM + ksw;
        } else {
            srcA[it] = A + (size_t)arow * KD + ksw;
        }
        srcB[it] = B + (MODE <= 1 ? (size_t)e * KD * NC : (size_t)0)
                     + (size_t)(n0 + row) * KD + ksw;
        dstA[it] = (char*)As + c * 16;
        dstB[it] = (char*)Bs + c * 16;
    }

    f32x4 acc[4][4] = {};

#pragma unroll 1
    for (int kk = 0; kk < KD; kk += 32) {
        if (kk) __syncthreads();
        gld16(dstA[0], srcA[0] + kk);
        gld16(dstA[1], srcA[1] + kk);
        gld16(dstB[0], srcB[0] + kk);
        gld16(dstB[1], srcB[1] + kk);
        __syncthreads();
        bf16x8 av[4], bv[4];
#pragma unroll
        for (int mi = 0; mi < 4; ++mi) {
            int r = wm * 64 + mi * 16 + (lane & 15);
            int s = (lane >> 4) ^ ((r >> 1) & 3);
            av[mi] = *(const bf16x8*)((const char*)As + r * 64 + s * 16);
        }
#pragma unroll
        for (int ni = 0; ni < 4; ++ni) {
            int r = wn * 64 + ni * 16 + (lane & 15);
            int s = (lane >> 4) ^ ((r >> 1) & 3);
            bv[ni] = *(const bf16x8*)((const char*)Bs + r * 64 + s * 16);
        }
#pragma unroll
        for (int mi = 0; mi < 4; ++mi)
#pragma unroll
            for (int ni = 0; ni < 4; ++ni)
                acc[mi][ni] = __builtin_amdgcn_mfma_f32_16x16x32_bf16(
                    av[mi], bv[ni], acc[mi][ni], 0, 0, 0);
    }

    // epilogue: C/D layout col = lane&15, row = (lane>>4)*4 + reg
    const int col = lane & 15, r4 = (lane >> 4) * 4;
#pragma unroll
    for (int mi = 0; mi < 4; ++mi) {
#pragma unroll
        for (int r = 0; r < 4; ++r) {
            int grow = tm * 128 + wm * 64 + mi * 16 + r4 + r;
            if (MODE <= 1 && grow >= mE) continue;
            float gate = 1.0f; int tok = 0; float g3 = 0.0f;
            if (MODE == 0) gate = agate[m0 + grow];
            if (MODE == 1) tok = atok[m0 + grow];
            if (MODE == 3) g3 = gsh[grow];
#pragma unroll
            for (int ni = 0; ni < 4; ++ni) {
                int gcol = n0 + wn * 64 + ni * 16 + col;
                float v = acc[mi][ni][r];
                if (MODE == 0) {
                    Hb[(size_t)(m0 + grow) * HDIM + gcol] = f2bf(gelu_f(v) * gate);
                } else if (MODE == 1) {
                    unsafeAtomicAdd(&Y[(size_t)tok * DDIM + gcol], v);
                } else if (MODE == 2) {
                    Hb[(size_t)grow * HDIM + gcol] = f2bf(gelu_f(v));
                } else {
                    Y[(size_t)grow * DDIM + gcol] = g3 * v;
                }
            }
        }
    }
}

// ---------------------------------------------------------------------------
extern "C" void kernel_launch(void* const* d_in, const int* in_sizes, int n_in,
                              void* d_out, int out_size, void* d_ws, size_t ws_size,
                              hipStream_t stream) {
    const float* x   = (const float*)d_in[0];
    const float* Wr  = (const float*)d_in[1];
    const float* Wg  = (const float*)d_in[2];
    const float* W1  = (const float*)d_in[3];
    const float* W2  = (const float*)d_in[4];
    const float* W1s = (const float*)d_in[5];
    const float* W2s = (const float*)d_in[6];
    float* out = (float*)d_out;

    char* ws = (char*)d_ws;
    size_t off = 0;
    auto carve = [&](size_t bytes) { char* p = ws + off; off += (bytes + 255) & ~(size_t)255; return p; };
    unsigned short* xb    = (unsigned short*)carve((size_t)N_TOK * DDIM * 2);
    unsigned short* w1t   = (unsigned short*)carve((size_t)NEXP * DDIM * HDIM * 2);
    unsigned short* w2t   = (unsigned short*)carve((size_t)NEXP * HDIM * DDIM * 2);
    unsigned short* w1st  = (unsigned short*)carve((size_t)DDIM * FDIM * 2);
    unsigned short* w2st  = (unsigned short*)carve((size_t)FDIM * DDIM * 2);
    unsigned short* hb    = (unsigned short*)carve((size_t)NASSIGN * HDIM * 2);
    unsigned short* hs    = (unsigned short*)carve((size_t)N_TOK * FDIM * 2);
    float* gsh            = (float*)carve((size_t)N_TOK * 4);
    int* t2i              = (int*)carve((size_t)N_TOK * 2 * 4);
    float* t2v            = (float*)carve((size_t)N_TOK * 2 * 4);
    int* atok             = (int*)carve((size_t)NASSIGN * 4);
    float* agate          = (float*)carve((size_t)NASSIGN * 4);
    float* imp            = (float*)carve(256);
    int* offs             = (int*)carve(256);
    int* fill             = (int*)carve(256);
    if (ws_size < off) return;   // fail loudly (output stays invalid)

    float* out_tail = out + (size_t)N_TOK * DDIM;

    hipLaunchKernelGGL(zero_small, dim3(1), dim3(256), 0, stream, imp);
    hipLaunchKernelGGL(cast_x_kernel, dim3(N_TOK * DDIM / 8 / 256), dim3(256), 0, stream, x, xb);
    hipLaunchKernelGGL((transpose_cast<DDIM, HDIM>), dim3(HDIM / 64, DDIM / 64, NEXP), dim3(256), 0, stream, W1, w1t);
    hipLaunchKernelGGL((transpose_cast<HDIM, DDIM>), dim3(DDIM / 64, HDIM / 64, NEXP), dim3(256), 0, stream, W2, w2t);
    hipLaunchKernelGGL((transpose_cast<DDIM, FDIM>), dim3(FDIM / 64, DDIM / 64, 1), dim3(256), 0, stream, W1s, w1st);
    hipLaunchKernelGGL((transpose_cast<FDIM, DDIM>), dim3(DDIM / 64, FDIM / 64, 1), dim3(256), 0, stream, W2s, w2st);
    hipLaunchKernelGGL(router_kernel, dim3(N_TOK / 4), dim3(256), 0, stream, x, Wr, Wg, gsh, t2i, t2v, imp);
    hipLaunchKernelGGL(scan_finalize, dim3(1), dim3(256), 0, stream, t2i, imp, offs, fill, out_tail);
    hipLaunchKernelGGL(build_assign, dim3(N_TOK / 256), dim3(256), 0, stream, t2i, t2v, offs, fill, atok, agate);

    // shared expert first: L2s plain-stores y, then expert L2 atomically adds
    hipLaunchKernelGGL((gemm_tile<2>), dim3(HDIM / 128, N_TOK / 128, 1), dim3(256), 0, stream,
                       xb, w1st, out, hs, offs, atok, agate, gsh);
    hipLaunchKernelGGL((gemm_tile<3>), dim3(DDIM / 128, N_TOK / 128, 1), dim3(256), 0, stream,
                       hs, w2st, out, nullptr, offs, atok, agate, gsh);
    hipLaunchKernelGGL((gemm_tile<0>), dim3(HDIM / 128, N_TOK / 128, NEXP), dim3(256), 0, stream,
                       xb, w1t, nullptr, hb, offs, atok, agate, gsh);
    hipLaunchKernelGGL((gemm_tile<1>), dim3(DDIM / 128, N_TOK / 128, NEXP), dim3(256), 0, stream,
                       hb, w2t, out, nullptr, offs, atok, agate, gsh);
}

// Round 2
// 685.465 us; speedup vs baseline: 1.0004x; 1.0004x over previous
//
#include <hip/hip_runtime.h>
#include <hip/hip_bf16.h>

// ---------------------------------------------------------------------------
// MoE layer: router (softmax, top-2) + 16 experts (D=2048 -> H=1024 -> D) +
// shared expert (D -> F=1024 -> D), gate-weighted combine, aux stats.
// Strategy: top-2 sparse dispatch + bf16 MFMA GEMMs (m97-style 128x128 tile,
// global_load_lds width 16, k-slot XOR swizzle for conflict-light ds_read_b128).
// ---------------------------------------------------------------------------

#define N_TOK 8192
#define DDIM  2048
#define NEXP  16
#define HDIM  1024
#define FDIM  1024
#define NASSIGN (N_TOK * 2)

typedef __attribute__((ext_vector_type(8))) short bf16x8;
typedef __attribute__((ext_vector_type(4))) float f32x4;
typedef __attribute__((ext_vector_type(8))) unsigned short u16x8;
typedef __attribute__((ext_vector_type(4))) unsigned short u16x4;

__device__ inline unsigned short f2bf(float f) {
    unsigned int u = __builtin_bit_cast(unsigned int, f);
    u += 0x7FFFu + ((u >> 16) & 1u);           // RNE (finite inputs only)
    return (unsigned short)(u >> 16);
}

__device__ inline float gelu_f(float v) {
    return 0.5f * v * (1.0f + erff(v * 0.7071067811865475f));
}

__device__ inline void gld16(void* lds, const void* g) {
    __builtin_amdgcn_global_load_lds(
        (const __attribute__((address_space(1))) unsigned int*)g,
        (__attribute__((address_space(3))) unsigned int*)lds, 16, 0, 0);
}

// ---------------------------------------------------------------------------
__global__ __launch_bounds__(256) void zero_small(float* imp) {
    if (threadIdx.x < NEXP) imp[threadIdx.x] = 0.0f;
}

// x fp32 -> bf16, 8 elems/thread
__global__ __launch_bounds__(256) void cast_x_kernel(const float* __restrict__ x,
                                                     unsigned short* __restrict__ xb) {
    size_t i = (size_t)blockIdx.x * 256 + threadIdx.x;   // group of 8
    const float4 a = ((const float4*)x)[i * 2];
    const float4 b = ((const float4*)x)[i * 2 + 1];
    u16x8 o;
    o[0] = f2bf(a.x); o[1] = f2bf(a.y); o[2] = f2bf(a.z); o[3] = f2bf(a.w);
    o[4] = f2bf(b.x); o[5] = f2bf(b.y); o[6] = f2bf(b.z); o[7] = f2bf(b.w);
    *(u16x8*)(xb + i * 8) = o;
}

// [R][C] fp32 -> [C][R] bf16, 64x64 LDS tiles, batched over blockIdx.z
template <int R, int C>
__global__ __launch_bounds__(256) void transpose_cast(const float* __restrict__ src,
                                                      unsigned short* __restrict__ dst) {
    __shared__ unsigned short t[64][66];
    const size_t zoff = (size_t)blockIdx.z * R * C;
    src += zoff; dst += zoff;
    const int r0 = blockIdx.y * 64, c0 = blockIdx.x * 64;
    const int tid = threadIdx.x;
    const int cr = tid >> 4;            // 0..15
    const int cc4 = (tid & 15) * 4;
#pragma unroll
    for (int it = 0; it < 4; ++it) {
        int row = cr + it * 16;
        const float4 v = *(const float4*)(src + (size_t)(r0 + row) * C + c0 + cc4);
        t[row][cc4 + 0] = f2bf(v.x); t[row][cc4 + 1] = f2bf(v.y);
        t[row][cc4 + 2] = f2bf(v.z); t[row][cc4 + 3] = f2bf(v.w);
    }
    __syncthreads();
#pragma unroll
    for (int it = 0; it < 4; ++it) {
        int cc = cr + it * 16;
        u16x4 o;
#pragma unroll
        for (int j = 0; j < 4; ++j) o[j] = t[cc4 + j][cc];
        *(u16x4*)(dst + (size_t)(c0 + cc) * R + r0 + cc4) = o;
    }
}

// ---------------------------------------------------------------------------
// Router: one wave per token. logits = x@Wr (16), gate = x@Wg; softmax; top-2.
__global__ __launch_bounds__(256) void router_kernel(
    const float* __restrict__ x, const float* __restrict__ Wr, const float* __restrict__ Wg,
    float* __restrict__ gsh, int* __restrict__ t2i, float* __restrict__ t2v,
    float* __restrict__ imp) {
    __shared__ float simp[NEXP];
    const int tid = threadIdx.x, lane = tid & 63, w = tid >> 6;
    if (tid < NEXP) simp[tid] = 0.0f;
    __syncthreads();
    const int n = blockIdx.x * 4 + w;
    const float* xr = x + (size_t)n * DDIM;
    float acc[NEXP];
#pragma unroll
    for (int e = 0; e < NEXP; ++e) acc[e] = 0.0f;
    float ag = 0.0f;
    for (int j = 0; j < DDIM / 64; ++j) {
        int d = lane + j * 64;
        float xv = xr[d];
        const float* wr = Wr + (size_t)d * NEXP;
#pragma unroll
        for (int e = 0; e < NEXP; ++e) acc[e] = fmaf(xv, wr[e], acc[e]);
        ag = fmaf(xv, Wg[d], ag);
    }
#pragma unroll
    for (int off = 32; off; off >>= 1) {
#pragma unroll
        for (int e = 0; e < NEXP; ++e) acc[e] += __shfl_xor(acc[e], off);
        ag += __shfl_xor(ag, off);
    }
    if (lane == 0) {
        float mx = acc[0];
#pragma unroll
        for (int e = 1; e < NEXP; ++e) mx = fmaxf(mx, acc[e]);
        float p[NEXP], s = 0.0f;
#pragma unroll
        for (int e = 0; e < NEXP; ++e) { p[e] = expf(acc[e] - mx); s += p[e]; }
        const float inv = 1.0f / s;
        int i1 = 0; float v1 = -1.0f;
#pragma unroll
        for (int e = 0; e < NEXP; ++e) {
            p[e] *= inv;
            if (p[e] > v1) { v1 = p[e]; i1 = e; }
        }
        int i2 = 0; float v2 = -1.0f;
#pragma unroll
        for (int e = 0; e < NEXP; ++e) {
            if (e != i1 && p[e] > v2) { v2 = p[e]; i2 = e; }
        }
        t2i[2 * n] = i1; t2i[2 * n + 1] = i2;
        t2v[2 * n] = v1; t2v[2 * n + 1] = v2;
        gsh[n] = 1.0f / (1.0f + expf(-ag));
#pragma unroll
        for (int e = 0; e < NEXP; ++e) atomicAdd(&simp[e], p[e]);
    }
    __syncthreads();
    if (tid < NEXP) unsafeAtomicAdd(&imp[tid], simp[tid]);
}

// Single block: histogram counts, exclusive scan -> offsets, aux outputs, fill=0
__global__ __launch_bounds__(256) void scan_finalize(
    const int* __restrict__ t2i, const float* __restrict__ imp,
    int* __restrict__ offs, int* __restrict__ fill, float* __restrict__ out_tail) {
    __shared__ int hist[NEXP];
    const int tid = threadIdx.x;
    if (tid < NEXP) hist[tid] = 0;
    __syncthreads();
    for (int i = tid; i < NASSIGN; i += 256) atomicAdd(&hist[t2i[i]], 1);
    __syncthreads();
    if (tid == 0) {
        int o = 0;
        for (int e = 0; e < NEXP; ++e) { offs[e] = o; o += hist[e]; }
        offs[NEXP] = o;
    }
    if (tid < NEXP) {
        fill[tid] = 0;
        out_tail[tid] = imp[tid] * (1.0f / (float)N_TOK);
        out_tail[NEXP + tid] = (float)hist[tid] / (float)NASSIGN;
    }
}

__global__ __launch_bounds__(256) void build_assign(
    const int* __restrict__ t2i, const float* __restrict__ t2v,
    const int* __restrict__ offs, int* __restrict__ fill,
    int* __restrict__ atok, float* __restrict__ agate) {
    const int n = blockIdx.x * 256 + threadIdx.x;
#pragma unroll
    for (int k = 0; k < 2; ++k) {
        int e = t2i[2 * n + k];
        int pos = offs[e] + atomicAdd(&fill[e], 1);
        atok[pos] = n;
        agate[pos] = t2v[2 * n + k];
    }
}

// ---------------------------------------------------------------------------
// GEMM: C[M][NC] = A[M][KD] * B^T[NC][KD]   (both bf16, fp32 accum)
// MODE 0: expert L1  (A = gathered x, out = gelu*gate -> Hb)
// MODE 1: expert L2  (A = Hb, out = atomicAdd into Y[token])
// MODE 2: shared L1  (A = x, out = gelu -> Hb)
// MODE 3: shared L2  (A = Hs, out = Y[row] = gsh*acc, plain store)
template <int MODE>
__global__ __launch_bounds__(256) void gemm_tile(
    const unsigned short* __restrict__ A, const unsigned short* __restrict__ B,
    float* __restrict__ Y, unsigned short* __restrict__ Hb,
    const int* __restrict__ offs, const int* __restrict__ atok,
    const float* __restrict__ agate, const float* __restrict__ gsh) {
    constexpr int KD = (MODE == 0 || MODE == 2) ? DDIM : HDIM;
    constexpr int NC = (MODE == 0 || MODE == 2) ? HDIM : DDIM;
    const int e = blockIdx.z;
    int m0 = 0, mE = N_TOK;
    if (MODE <= 1) { m0 = offs[e]; mE = offs[e + 1] - m0; }
    const int tm = blockIdx.y;
    if (tm * 128 >= mE) return;
    const int n0 = blockIdx.x * 128;

    __shared__ __align__(16) unsigned short As[128 * 32];
    __shared__ __align__(16) unsigned short Bs[128 * 32];

    const int tid = threadIdx.x, lane = tid & 63;
    const int wid = tid >> 6, wm = wid >> 1, wn = wid & 1;

    // staging descriptors: 2 chunks of A + 2 of B per thread per K-step
    const unsigned short* srcA[2];
    const unsigned short* srcB[2];
    char* dstA[2];
    char* dstB[2];
#pragma unroll
    for (int it = 0; it < 2; ++it) {
        int c = tid + it * 256;
        int row = c >> 2, slot = c & 3;
        int ksw = (slot ^ ((row >> 1) & 3)) * 8;   // pre-swizzled global k-chunk
        int arow = tm * 128 + row;
        if (MODE == 0) {
            int ar = arow < mE ? arow : mE - 1;
            srcA[it] = A + (size_t)atok[m0 + ar] * DDIM + ksw;
        } else if (MODE == 1) {
            int ar = arow < mE ? arow : mE - 1;
            srcA[it] = A + (size_t)(m0 + ar) * HDIM + ksw;
        } else {
            srcA[it] = A + (size_t)arow * KD + ksw;
        }
        srcB[it] = B + (MODE <= 1 ? (size_t)e * KD * NC : (size_t)0)
                     + (size_t)(n0 + row) * KD + ksw;
        dstA[it] = (char*)As + c * 16;
        dstB[it] = (char*)Bs + c * 16;
    }

    f32x4 acc[4][4] = {};

#pragma unroll 1
    for (int kk = 0; kk < KD; kk += 32) {
        if (kk) __syncthreads();
        gld16(dstA[0], srcA[0] + kk);
        gld16(dstA[1], srcA[1] + kk);
        gld16(dstB[0], srcB[0] + kk);
        gld16(dstB[1], srcB[1] + kk);
        __syncthreads();
        bf16x8 av[4], bv[4];
#pragma unroll
        for (int mi = 0; mi < 4; ++mi) {
            int r = wm * 64 + mi * 16 + (lane & 15);
            int s = (lane >> 4) ^ ((r >> 1) & 3);
            av[mi] = *(const bf16x8*)((const char*)As + r * 64 + s * 16);
        }
#pragma unroll
        for (int ni = 0; ni < 4; ++ni) {
            int r = wn * 64 + ni * 16 + (lane & 15);
            int s = (lane >> 4) ^ ((r >> 1) & 3);
            bv[ni] = *(const bf16x8*)((const char*)Bs + r * 64 + s * 16);
        }
#pragma unroll
        for (int mi = 0; mi < 4; ++mi)
#pragma unroll
            for (int ni = 0; ni < 4; ++ni)
                acc[mi][ni] = __builtin_amdgcn_mfma_f32_16x16x32_bf16(
                    av[mi], bv[ni], acc[mi][ni], 0, 0, 0);
    }

    // epilogue: C/D layout col = lane&15, row = (lane>>4)*4 + reg
    const int col = lane & 15, r4 = (lane >> 4) * 4;
#pragma unroll
    for (int mi = 0; mi < 4; ++mi) {
#pragma unroll
        for (int r = 0; r < 4; ++r) {
            int grow = tm * 128 + wm * 64 + mi * 16 + r4 + r;
            if (MODE <= 1 && grow >= mE) continue;
            float gate = 1.0f; int tok = 0; float g3 = 0.0f;
            if (MODE == 0) gate = agate[m0 + grow];
            if (MODE == 1) tok = atok[m0 + grow];
            if (MODE == 3) g3 = gsh[grow];
#pragma unroll
            for (int ni = 0; ni < 4; ++ni) {
                int gcol = n0 + wn * 64 + ni * 16 + col;
                float v = acc[mi][ni][r];
                if (MODE == 0) {
                    Hb[(size_t)(m0 + grow) * HDIM + gcol] = f2bf(gelu_f(v) * gate);
                } else if (MODE == 1) {
                    unsafeAtomicAdd(&Y[(size_t)tok * DDIM + gcol], v);
                } else if (MODE == 2) {
                    Hb[(size_t)grow * HDIM + gcol] = f2bf(gelu_f(v));
                } else {
                    Y[(size_t)grow * DDIM + gcol] = g3 * v;
                }
            }
        }
    }
}

// ---------------------------------------------------------------------------
extern "C" void kernel_launch(void* const* d_in, const int* in_sizes, int n_in,
                              void* d_out, int out_size, void* d_ws, size_t ws_size,
                              hipStream_t stream) {
    const float* x   = (const float*)d_in[0];
    const float* Wr  = (const float*)d_in[1];
    const float* Wg  = (const float*)d_in[2];
    const float* W1  = (const float*)d_in[3];
    const float* W2  = (const float*)d_in[4];
    const float* W1s = (const float*)d_in[5];
    const float* W2s = (const float*)d_in[6];
    float* out = (float*)d_out;

    char* ws = (char*)d_ws;
    size_t off = 0;
    auto carve = [&](size_t bytes) { char* p = ws + off; off += (bytes + 255) & ~(size_t)255; return p; };
    unsigned short* xb    = (unsigned short*)carve((size_t)N_TOK * DDIM * 2);
    unsigned short* w1t   = (unsigned short*)carve((size_t)NEXP * DDIM * HDIM * 2);
    unsigned short* w2t   = (unsigned short*)carve((size_t)NEXP * HDIM * DDIM * 2);
    unsigned short* w1st  = (unsigned short*)carve((size_t)DDIM * FDIM * 2);
    unsigned short* w2st  = (unsigned short*)carve((size_t)FDIM * DDIM * 2);
    unsigned short* hb    = (unsigned short*)carve((size_t)NASSIGN * HDIM * 2);
    unsigned short* hs    = (unsigned short*)carve((size_t)N_TOK * FDIM * 2);
    float* gsh            = (float*)carve((size_t)N_TOK * 4);
    int* t2i              = (int*)carve((size_t)N_TOK * 2 * 4);
    float* t2v            = (float*)carve((size_t)N_TOK * 2 * 4);
    int* atok             = (int*)carve((size_t)NASSIGN * 4);
    float* agate          = (float*)carve((size_t)NASSIGN * 4);
    float* imp            = (float*)carve(256);
    int* offs             = (int*)carve(256);
    int* fill             = (int*)carve(256);
    if (ws_size < off) return;   // fail loudly (output stays invalid)

    float* out_tail = out + (size_t)N_TOK * DDIM;

    hipLaunchKernelGGL(zero_small, dim3(1), dim3(256), 0, stream, imp);
    hipLaunchKernelGGL(cast_x_kernel, dim3(N_TOK * DDIM / 8 / 256), dim3(256), 0, stream, x, xb);
    hipLaunchKernelGGL((transpose_cast<DDIM, HDIM>), dim3(HDIM / 64, DDIM / 64, NEXP), dim3(256), 0, stream, W1, w1t);
    hipLaunchKernelGGL((transpose_cast<HDIM, DDIM>), dim3(DDIM / 64, HDIM / 64, NEXP), dim3(256), 0, stream, W2, w2t);
    hipLaunchKernelGGL((transpose_cast<DDIM, FDIM>), dim3(FDIM / 64, DDIM / 64, 1), dim3(256), 0, stream, W1s, w1st);
    hipLaunchKernelGGL((transpose_cast<FDIM, DDIM>), dim3(DDIM / 64, FDIM / 64, 1), dim3(256), 0, stream, W2s, w2st);
    hipLaunchKernelGGL(router_kernel, dim3(N_TOK / 4), dim3(256), 0, stream, x, Wr, Wg, gsh, t2i, t2v, imp);
    hipLaunchKernelGGL(scan_finalize, dim3(1), dim3(256), 0, stream, t2i, imp, offs, fill, out_tail);
    hipLaunchKernelGGL(build_assign, dim3(N_TOK / 256), dim3(256), 0, stream, t2i, t2v, offs, fill, atok, agate);

    // shared expert first: L2s plain-stores y, then expert L2 atomically adds
    hipLaunchKernelGGL((gemm_tile<2>), dim3(HDIM / 128, N_TOK / 128, 1), dim3(256), 0, stream,
                       xb, w1st, out, hs, offs, atok, agate, gsh);
    hipLaunchKernelGGL((gemm_tile<3>), dim3(DDIM / 128, N_TOK / 128, 1), dim3(256), 0, stream,
                       hs, w2st, out, nullptr, offs, atok, agate, gsh);
    hipLaunchKernelGGL((gemm_tile<0>), dim3(HDIM / 128, N_TOK / 128, NEXP), dim3(256), 0, stream,
                       xb, w1t, nullptr, hb, offs, atok, agate, gsh);
    hipLaunchKernelGGL((gemm_tile<1>), dim3(DDIM / 128, N_TOK / 128, NEXP), dim3(256), 0, stream,
                       hb, w2t, out, nullptr, offs, atok, agate, gsh);
}

// Round 3
// 685.012 us; speedup vs baseline: 1.0010x; 1.0007x over previous
//
#include <hip/hip_runtime.h>
#include <hip/hip_bf16.h>

// ---------------------------------------------------------------------------
// MoE layer: router (softmax, top-2) + 16 experts (D=2048 -> H=1024 -> D) +
// shared expert (D -> F=1024 -> D), gate-weighted combine, aux stats.
// Strategy: top-2 sparse dispatch + bf16 MFMA GEMMs (m97-style 128x128 tile,
// global_load_lds width 16, k-slot XOR swizzle for conflict-light ds_read_b128).
// ---------------------------------------------------------------------------

#define N_TOK 8192
#define DDIM  2048
#define NEXP  16
#define HDIM  1024
#define FDIM  1024
#define NASSIGN (N_TOK * 2)

typedef __attribute__((ext_vector_type(8))) short bf16x8;
typedef __attribute__((ext_vector_type(4))) float f32x4;
typedef __attribute__((ext_vector_type(8))) unsigned short u16x8;
typedef __attribute__((ext_vector_type(4))) unsigned short u16x4;

__device__ inline unsigned short f2bf(float f) {
    unsigned int u = __builtin_bit_cast(unsigned int, f);
    u += 0x7FFFu + ((u >> 16) & 1u);           // RNE (finite inputs only)
    return (unsigned short)(u >> 16);
}

__device__ inline float gelu_f(float v) {
    return 0.5f * v * (1.0f + erff(v * 0.7071067811865475f));
}

__device__ inline void gld16(void* lds, const void* g) {
    __builtin_amdgcn_global_load_lds(
        (const __attribute__((address_space(1))) unsigned int*)g,
        (__attribute__((address_space(3))) unsigned int*)lds, 16, 0, 0);
}

// ---------------------------------------------------------------------------
__global__ __launch_bounds__(256) void zero_small(float* imp) {
    if (threadIdx.x < NEXP) imp[threadIdx.x] = 0.0f;
}

// x fp32 -> bf16, 8 elems/thread
__global__ __launch_bounds__(256) void cast_x_kernel(const float* __restrict__ x,
                                                     unsigned short* __restrict__ xb) {
    size_t i = (size_t)blockIdx.x * 256 + threadIdx.x;   // group of 8
    const float4 a = ((const float4*)x)[i * 2];
    const float4 b = ((const float4*)x)[i * 2 + 1];
    u16x8 o;
    o[0] = f2bf(a.x); o[1] = f2bf(a.y); o[2] = f2bf(a.z); o[3] = f2bf(a.w);
    o[4] = f2bf(b.x); o[5] = f2bf(b.y); o[6] = f2bf(b.z); o[7] = f2bf(b.w);
    *(u16x8*)(xb + i * 8) = o;
}

// [R][C] fp32 -> [C][R] bf16, 64x64 LDS tiles, batched over blockIdx.z
template <int R, int C>
__global__ __launch_bounds__(256) void transpose_cast(const float* __restrict__ src,
                                                      unsigned short* __restrict__ dst) {
    __shared__ unsigned short t[64][66];
    const size_t zoff = (size_t)blockIdx.z * R * C;
    src += zoff; dst += zoff;
    const int r0 = blockIdx.y * 64, c0 = blockIdx.x * 64;
    const int tid = threadIdx.x;
    const int cr = tid >> 4;            // 0..15
    const int cc4 = (tid & 15) * 4;
#pragma unroll
    for (int it = 0; it < 4; ++it) {
        int row = cr + it * 16;
        const float4 v = *(const float4*)(src + (size_t)(r0 + row) * C + c0 + cc4);
        t[row][cc4 + 0] = f2bf(v.x); t[row][cc4 + 1] = f2bf(v.y);
        t[row][cc4 + 2] = f2bf(v.z); t[row][cc4 + 3] = f2bf(v.w);
    }
    __syncthreads();
#pragma unroll
    for (int it = 0; it < 4; ++it) {
        int cc = cr + it * 16;
        u16x4 o;
#pragma unroll
        for (int j = 0; j < 4; ++j) o[j] = t[cc4 + j][cc];
        *(u16x4*)(dst + (size_t)(c0 + cc) * R + r0 + cc4) = o;
    }
}

// ---------------------------------------------------------------------------
// Router: one wave per token. logits = x@Wr (16), gate = x@Wg; softmax; top-2.
__global__ __launch_bounds__(256) void router_kernel(
    const float* __restrict__ x, const float* __restrict__ Wr, const float* __restrict__ Wg,
    float* __restrict__ gsh, int* __restrict__ t2i, float* __restrict__ t2v,
    float* __restrict__ imp) {
    __shared__ float simp[NEXP];
    const int tid = threadIdx.x, lane = tid & 63, w = tid >> 6;
    if (tid < NEXP) simp[tid] = 0.0f;
    __syncthreads();
    const int n = blockIdx.x * 4 + w;
    const float* xr = x + (size_t)n * DDIM;
    float acc[NEXP];
#pragma unroll
    for (int e = 0; e < NEXP; ++e) acc[e] = 0.0f;
    float ag = 0.0f;
    for (int j = 0; j < DDIM / 64; ++j) {
        int d = lane + j * 64;
        float xv = xr[d];
        const float* wr = Wr + (size_t)d * NEXP;
#pragma unroll
        for (int e = 0; e < NEXP; ++e) acc[e] = fmaf(xv, wr[e], acc[e]);
        ag = fmaf(xv, Wg[d], ag);
    }
#pragma unroll
    for (int off = 32; off; off >>= 1) {
#pragma unroll
        for (int e = 0; e < NEXP; ++e) acc[e] += __shfl_xor(acc[e], off);
        ag += __shfl_xor(ag, off);
    }
    if (lane == 0) {
        float mx = acc[0];
#pragma unroll
        for (int e = 1; e < NEXP; ++e) mx = fmaxf(mx, acc[e]);
        float p[NEXP], s = 0.0f;
#pragma unroll
        for (int e = 0; e < NEXP; ++e) { p[e] = expf(acc[e] - mx); s += p[e]; }
        const float inv = 1.0f / s;
        int i1 = 0; float v1 = -1.0f;
#pragma unroll
        for (int e = 0; e < NEXP; ++e) {
            p[e] *= inv;
            if (p[e] > v1) { v1 = p[e]; i1 = e; }
        }
        int i2 = 0; float v2 = -1.0f;
#pragma unroll
        for (int e = 0; e < NEXP; ++e) {
            if (e != i1 && p[e] > v2) { v2 = p[e]; i2 = e; }
        }
        t2i[2 * n] = i1; t2i[2 * n + 1] = i2;
        t2v[2 * n] = v1; t2v[2 * n + 1] = v2;
        gsh[n] = 1.0f / (1.0f + expf(-ag));
#pragma unroll
        for (int e = 0; e < NEXP; ++e) atomicAdd(&simp[e], p[e]);
    }
    __syncthreads();
    if (tid < NEXP) unsafeAtomicAdd(&imp[tid], simp[tid]);
}

// Single block: histogram counts, exclusive scan -> offsets, aux outputs, fill=0
__global__ __launch_bounds__(256) void scan_finalize(
    const int* __restrict__ t2i, const float* __restrict__ imp,
    int* __restrict__ offs, int* __restrict__ fill, float* __restrict__ out_tail) {
    __shared__ int hist[NEXP];
    const int tid = threadIdx.x;
    if (tid < NEXP) hist[tid] = 0;
    __syncthreads();
    for (int i = tid; i < NASSIGN; i += 256) atomicAdd(&hist[t2i[i]], 1);
    __syncthreads();
    if (tid == 0) {
        int o = 0;
        for (int e = 0; e < NEXP; ++e) { offs[e] = o; o += hist[e]; }
        offs[NEXP] = o;
    }
    if (tid < NEXP) {
        fill[tid] = 0;
        out_tail[tid] = imp[tid] * (1.0f / (float)N_TOK);
        out_tail[NEXP + tid] = (float)hist[tid] / (float)NASSIGN;
    }
}

__global__ __launch_bounds__(256) void build_assign(
    const int* __restrict__ t2i, const float* __restrict__ t2v,
    const int* __restrict__ offs, int* __restrict__ fill,
    int* __restrict__ atok, float* __restrict__ agate) {
    const int n = blockIdx.x * 256 + threadIdx.x;
#pragma unroll
    for (int k = 0; k < 2; ++k) {
        int e = t2i[2 * n + k];
        int pos = offs[e] + atomicAdd(&fill[e], 1);
        atok[pos] = n;
        agate[pos] = t2v[2 * n + k];
    }
}

// ---------------------------------------------------------------------------
// GEMM: C[M][NC] = A[M][KD] * B^T[NC][KD]   (both bf16, fp32 accum)
// MODE 0: expert L1  (A = gathered x, out = gelu*gate -> Hb)
// MODE 1: expert L2  (A = Hb, out = atomicAdd into Y[token])
// MODE 2: shared L1  (A = x, out = gelu -> Hb)
// MODE 3: shared L2  (A = Hs, out = Y[row] = gsh*acc, plain store)
template <int MODE>
__global__ __launch_bounds__(256) void gemm_tile(
    const unsigned short* __restrict__ A, const unsigned short* __restrict__ B,
    float* __restrict__ Y, unsigned short* __restrict__ Hb,
    const int* __restrict__ offs, const int* __restrict__ atok,
    const float* __restrict__ agate, const float* __restrict__ gsh) {
    constexpr int KD = (MODE == 0 || MODE == 2) ? DDIM : HDIM;
    constexpr int NC = (MODE == 0 || MODE == 2) ? HDIM : DDIM;
    const int e = blockIdx.z;
    int m0 = 0, mE = N_TOK;
    if (MODE <= 1) { m0 = offs[e]; mE = offs[e + 1] - m0; }
    const int tm = blockIdx.y;
    if (tm * 128 >= mE) return;
    const int n0 = blockIdx.x * 128;

    __shared__ __align__(16) unsigned short As[128 * 32];
    __shared__ __align__(16) unsigned short Bs[128 * 32];

    const int tid = threadIdx.x, lane = tid & 63;
    const int wid = tid >> 6, wm = wid >> 1, wn = wid & 1;

    // staging descriptors: 2 chunks of A + 2 of B per thread per K-step
    const unsigned short* srcA[2];
    const unsigned short* srcB[2];
    char* dstA[2];
    char* dstB[2];
#pragma unroll
    for (int it = 0; it < 2; ++it) {
        int c = tid + it * 256;
        int row = c >> 2, slot = c & 3;
        int ksw = (slot ^ ((row >> 1) & 3)) * 8;   // pre-swizzled global k-chunk
        int arow = tm * 128 + row;
        if (MODE == 0) {
            int ar = arow < mE ? arow : mE - 1;
            srcA[it] = A + (size_t)atok[m0 + ar] * DDIM + ksw;
        } else if (MODE == 1) {
            int ar = arow < mE ? arow : mE - 1;
            srcA[it] = A + (size_t)(m0 + ar) * HDIM + ksw;
        } else {
            srcA[it] = A + (size_t)arow * KD + ksw;
        }
        srcB[it] = B + (MODE <= 1 ? (size_t)e * KD * NC : (size_t)0)
                     + (size_t)(n0 + row) * KD + ksw;
        dstA[it] = (char*)As + c * 16;
        dstB[it] = (char*)Bs + c * 16;
    }

    f32x4 acc[4][4] = {};

#pragma unroll 1
    for (int kk = 0; kk < KD; kk += 32) {
        if (kk) __syncthreads();
        gld16(dstA[0], srcA[0] + kk);
        gld16(dstA[1], srcA[1] + kk);
        gld16(dstB[0], srcB[0] + kk);
        gld16(dstB[1], srcB[1] + kk);
        __syncthreads();
        bf16x8 av[4], bv[4];
#pragma unroll
        for (int mi = 0; mi < 4; ++mi) {
            int r = wm * 64 + mi * 16 + (lane & 15);
            int s = (lane >> 4) ^ ((r >> 1) & 3);
            av[mi] = *(const bf16x8*)((const char*)As + r * 64 + s * 16);
        }
#pragma unroll
        for (int ni = 0; ni < 4; ++ni) {
            int r = wn * 64 + ni * 16 + (lane & 15);
            int s = (lane >> 4) ^ ((r >> 1) & 3);
            bv[ni] = *(const bf16x8*)((const char*)Bs + r * 64 + s * 16);
        }
#pragma unroll
        for (int mi = 0; mi < 4; ++mi)
#pragma unroll
            for (int ni = 0; ni < 4; ++ni)
                acc[mi][ni] = __builtin_amdgcn_mfma_f32_16x16x32_bf16(
                    av[mi], bv[ni], acc[mi][ni], 0, 0, 0);
    }

    // epilogue: C/D layout col = lane&15, row = (lane>>4)*4 + reg
    const int col = lane & 15, r4 = (lane >> 4) * 4;
#pragma unroll
    for (int mi = 0; mi < 4; ++mi) {
#pragma unroll
        for (int r = 0; r < 4; ++r) {
            int grow = tm * 128 + wm * 64 + mi * 16 + r4 + r;
            if (MODE <= 1 && grow >= mE) continue;
            float gate = 1.0f; int tok = 0; float g3 = 0.0f;
            if (MODE == 0) gate = agate[m0 + grow];
            if (MODE == 1) tok = atok[m0 + grow];
            if (MODE == 3) g3 = gsh[grow];
#pragma unroll
            for (int ni = 0; ni < 4; ++ni) {
                int gcol = n0 + wn * 64 + ni * 16 + col;
                float v = acc[mi][ni][r];
                if (MODE == 0) {
                    Hb[(size_t)(m0 + grow) * HDIM + gcol] = f2bf(gelu_f(v) * gate);
                } else if (MODE == 1) {
                    unsafeAtomicAdd(&Y[(size_t)tok * DDIM + gcol], v);
                } else if (MODE == 2) {
                    Hb[(size_t)grow * HDIM + gcol] = f2bf(gelu_f(v));
                } else {
                    Y[(size_t)grow * DDIM + gcol] = g3 * v;
                }
            }
        }
    }
}

// ---------------------------------------------------------------------------
extern "C" void kernel_launch(void* const* d_in, const int* in_sizes, int n_in,
                              void* d_out, int out_size, void* d_ws, size_t ws_size,
                              hipStream_t stream) {
    const float* x   = (const float*)d_in[0];
    const float* Wr  = (const float*)d_in[1];
    const float* Wg  = (const float*)d_in[2];
    const float* W1  = (const float*)d_in[3];
    const float* W2  = (const float*)d_in[4];
    const float* W1s = (const float*)d_in[5];
    const float* W2s = (const float*)d_in[6];
    float* out = (float*)d_out;

    char* ws = (char*)d_ws;
    size_t off = 0;
    auto carve = [&](size_t bytes) { char* p = ws + off; off += (bytes + 255) & ~(size_t)255; return p; };
    unsigned short* xb    = (unsigned short*)carve((size_t)N_TOK * DDIM * 2);
    unsigned short* w1t   = (unsigned short*)carve((size_t)NEXP * DDIM * HDIM * 2);
    unsigned short* w2t   = (unsigned short*)carve((size_t)NEXP * HDIM * DDIM * 2);
    unsigned short* w1st  = (unsigned short*)carve((size_t)DDIM * FDIM * 2);
    unsigned short* w2st  = (unsigned short*)carve((size_t)FDIM * DDIM * 2);
    unsigned short* hb    = (unsigned short*)carve((size_t)NASSIGN * HDIM * 2);
    unsigned short* hs    = (unsigned short*)carve((size_t)N_TOK * FDIM * 2);
    float* gsh            = (float*)carve((size_t)N_TOK * 4);
    int* t2i              = (int*)carve((size_t)N_TOK * 2 * 4);
    float* t2v            = (float*)carve((size_t)N_TOK * 2 * 4);
    int* atok             = (int*)carve((size_t)NASSIGN * 4);
    float* agate          = (float*)carve((size_t)NASSIGN * 4);
    float* imp            = (float*)carve(256);
    int* offs             = (int*)carve(256);
    int* fill             = (int*)carve(256);
    if (ws_size < off) return;   // fail loudly (output stays invalid)

    float* out_tail = out + (size_t)N_TOK * DDIM;

    hipLaunchKernelGGL(zero_small, dim3(1), dim3(256), 0, stream, imp);
    hipLaunchKernelGGL(cast_x_kernel, dim3(N_TOK * DDIM / 8 / 256), dim3(256), 0, stream, x, xb);
    hipLaunchKernelGGL((transpose_cast<DDIM, HDIM>), dim3(HDIM / 64, DDIM / 64, NEXP), dim3(256), 0, stream, W1, w1t);
    hipLaunchKernelGGL((transpose_cast<HDIM, DDIM>), dim3(DDIM / 64, HDIM / 64, NEXP), dim3(256), 0, stream, W2, w2t);
    hipLaunchKernelGGL((transpose_cast<DDIM, FDIM>), dim3(FDIM / 64, DDIM / 64, 1), dim3(256), 0, stream, W1s, w1st);
    hipLaunchKernelGGL((transpose_cast<FDIM, DDIM>), dim3(DDIM / 64, FDIM / 64, 1), dim3(256), 0, stream, W2s, w2st);
    hipLaunchKernelGGL(router_kernel, dim3(N_TOK / 4), dim3(256), 0, stream, x, Wr, Wg, gsh, t2i, t2v, imp);
    hipLaunchKernelGGL(scan_finalize, dim3(1), dim3(256), 0, stream, t2i, imp, offs, fill, out_tail);
    hipLaunchKernelGGL(build_assign, dim3(N_TOK / 256), dim3(256), 0, stream, t2i, t2v, offs, fill, atok, agate);

    // shared expert first: L2s plain-stores y, then expert L2 atomically adds
    hipLaunchKernelGGL((gemm_tile<2>), dim3(HDIM / 128, N_TOK / 128, 1), dim3(256), 0, stream,
                       xb, w1st, out, hs, offs, atok, agate, gsh);
    hipLaunchKernelGGL((gemm_tile<3>), dim3(DDIM / 128, N_TOK / 128, 1), dim3(256), 0, stream,
                       hs, w2st, out, nullptr, offs, atok, agate, gsh);
    hipLaunchKernelGGL((gemm_tile<0>), dim3(HDIM / 128, N_TOK / 128, NEXP), dim3(256), 0, stream,
                       xb, w1t, nullptr, hb, offs, atok, agate, gsh);
    hipLaunchKernelGGL((gemm_tile<1>), dim3(DDIM / 128, N_TOK / 128, NEXP), dim3(256), 0, stream,
                       hb, w2t, out, nullptr, offs, atok, agate, gsh);
}

// Round 4
// 684.731 us; speedup vs baseline: 1.0015x; 1.0004x over previous
//
#include <hip/hip_runtime.h>
#include <hip/hip_bf16.h>

// ---------------------------------------------------------------------------
// MoE layer: router (softmax, top-2) + 16 experts (D=2048 -> H=1024 -> D) +
// shared expert (D -> F=1024 -> D), gate-weighted combine, aux stats.
// Strategy: top-2 sparse dispatch + bf16 MFMA GEMMs (m97-style 128x128 tile,
// global_load_lds width 16, k-slot XOR swizzle for conflict-light ds_read_b128).
// ---------------------------------------------------------------------------

#define N_TOK 8192
#define DDIM  2048
#define NEXP  16
#define HDIM  1024
#define FDIM  1024
#define NASSIGN (N_TOK * 2)

typedef __attribute__((ext_vector_type(8))) short bf16x8;
typedef __attribute__((ext_vector_type(4))) float f32x4;
typedef __attribute__((ext_vector_type(8))) unsigned short u16x8;
typedef __attribute__((ext_vector_type(4))) unsigned short u16x4;

__device__ inline unsigned short f2bf(float f) {
    unsigned int u = __builtin_bit_cast(unsigned int, f);
    u += 0x7FFFu + ((u >> 16) & 1u);           // RNE (finite inputs only)
    return (unsigned short)(u >> 16);
}

__device__ inline float gelu_f(float v) {
    return 0.5f * v * (1.0f + erff(v * 0.7071067811865475f));
}

__device__ inline void gld16(void* lds, const void* g) {
    __builtin_amdgcn_global_load_lds(
        (const __attribute__((address_space(1))) unsigned int*)g,
        (__attribute__((address_space(3))) unsigned int*)lds, 16, 0, 0);
}

// ---------------------------------------------------------------------------
__global__ __launch_bounds__(256) void zero_small(float* imp) {
    if (threadIdx.x < NEXP) imp[threadIdx.x] = 0.0f;
}

// x fp32 -> bf16, 8 elems/thread
__global__ __launch_bounds__(256) void cast_x_kernel(const float* __restrict__ x,
                                                     unsigned short* __restrict__ xb) {
    size_t i = (size_t)blockIdx.x * 256 + threadIdx.x;   // group of 8
    const float4 a = ((const float4*)x)[i * 2];
    const float4 b = ((const float4*)x)[i * 2 + 1];
    u16x8 o;
    o[0] = f2bf(a.x); o[1] = f2bf(a.y); o[2] = f2bf(a.z); o[3] = f2bf(a.w);
    o[4] = f2bf(b.x); o[5] = f2bf(b.y); o[6] = f2bf(b.z); o[7] = f2bf(b.w);
    *(u16x8*)(xb + i * 8) = o;
}

// [R][C] fp32 -> [C][R] bf16, 64x64 LDS tiles, batched over blockIdx.z
template <int R, int C>
__global__ __launch_bounds__(256) void transpose_cast(const float* __restrict__ src,
                                                      unsigned short* __restrict__ dst) {
    __shared__ unsigned short t[64][66];
    const size_t zoff = (size_t)blockIdx.z * R * C;
    src += zoff; dst += zoff;
    const int r0 = blockIdx.y * 64, c0 = blockIdx.x * 64;
    const int tid = threadIdx.x;
    const int cr = tid >> 4;            // 0..15
    const int cc4 = (tid & 15) * 4;
#pragma unroll
    for (int it = 0; it < 4; ++it) {
        int row = cr + it * 16;
        const float4 v = *(const float4*)(src + (size_t)(r0 + row) * C + c0 + cc4);
        t[row][cc4 + 0] = f2bf(v.x); t[row][cc4 + 1] = f2bf(v.y);
        t[row][cc4 + 2] = f2bf(v.z); t[row][cc4 + 3] = f2bf(v.w);
    }
    __syncthreads();
#pragma unroll
    for (int it = 0; it < 4; ++it) {
        int cc = cr + it * 16;
        u16x4 o;
#pragma unroll
        for (int j = 0; j < 4; ++j) o[j] = t[cc4 + j][cc];
        *(u16x4*)(dst + (size_t)(c0 + cc) * R + r0 + cc4) = o;
    }
}

// ---------------------------------------------------------------------------
// Router: one wave per token. logits = x@Wr (16), gate = x@Wg; softmax; top-2.
__global__ __launch_bounds__(256) void router_kernel(
    const float* __restrict__ x, const float* __restrict__ Wr, const float* __restrict__ Wg,
    float* __restrict__ gsh, int* __restrict__ t2i, float* __restrict__ t2v,
    float* __restrict__ imp) {
    __shared__ float simp[NEXP];
    const int tid = threadIdx.x, lane = tid & 63, w = tid >> 6;
    if (tid < NEXP) simp[tid] = 0.0f;
    __syncthreads();
    const int n = blockIdx.x * 4 + w;
    const float* xr = x + (size_t)n * DDIM;
    float acc[NEXP];
#pragma unroll
    for (int e = 0; e < NEXP; ++e) acc[e] = 0.0f;
    float ag = 0.0f;
    for (int j = 0; j < DDIM / 64; ++j) {
        int d = lane + j * 64;
        float xv = xr[d];
        const float* wr = Wr + (size_t)d * NEXP;
#pragma unroll
        for (int e = 0; e < NEXP; ++e) acc[e] = fmaf(xv, wr[e], acc[e]);
        ag = fmaf(xv, Wg[d], ag);
    }
#pragma unroll
    for (int off = 32; off; off >>= 1) {
#pragma unroll
        for (int e = 0; e < NEXP; ++e) acc[e] += __shfl_xor(acc[e], off);
        ag += __shfl_xor(ag, off);
    }
    if (lane == 0) {
        float mx = acc[0];
#pragma unroll
        for (int e = 1; e < NEXP; ++e) mx = fmaxf(mx, acc[e]);
        float p[NEXP], s = 0.0f;
#pragma unroll
        for (int e = 0; e < NEXP; ++e) { p[e] = expf(acc[e] - mx); s += p[e]; }
        const float inv = 1.0f / s;
        int i1 = 0; float v1 = -1.0f;
#pragma unroll
        for (int e = 0; e < NEXP; ++e) {
            p[e] *= inv;
            if (p[e] > v1) { v1 = p[e]; i1 = e; }
        }
        int i2 = 0; float v2 = -1.0f;
#pragma unroll
        for (int e = 0; e < NEXP; ++e) {
            if (e != i1 && p[e] > v2) { v2 = p[e]; i2 = e; }
        }
        t2i[2 * n] = i1; t2i[2 * n + 1] = i2;
        t2v[2 * n] = v1; t2v[2 * n + 1] = v2;
        gsh[n] = 1.0f / (1.0f + expf(-ag));
#pragma unroll
        for (int e = 0; e < NEXP; ++e) atomicAdd(&simp[e], p[e]);
    }
    __syncthreads();
    if (tid < NEXP) unsafeAtomicAdd(&imp[tid], simp[tid]);
}

// Single block: histogram counts, exclusive scan -> offsets, aux outputs, fill=0
__global__ __launch_bounds__(256) void scan_finalize(
    const int* __restrict__ t2i, const float* __restrict__ imp,
    int* __restrict__ offs, int* __restrict__ fill, float* __restrict__ out_tail) {
    __shared__ int hist[NEXP];
    const int tid = threadIdx.x;
    if (tid < NEXP) hist[tid] = 0;
    __syncthreads();
    for (int i = tid; i < NASSIGN; i += 256) atomicAdd(&hist[t2i[i]], 1);
    __syncthreads();
    if (tid == 0) {
        int o = 0;
        for (int e = 0; e < NEXP; ++e) { offs[e] = o; o += hist[e]; }
        offs[NEXP] = o;
    }
    if (tid < NEXP) {
        fill[tid] = 0;
        out_tail[tid] = imp[tid] * (1.0f / (float)N_TOK);
        out_tail[NEXP + tid] = (float)hist[tid] / (float)NASSIGN;
    }
}

__global__ __launch_bounds__(256) void build_assign(
    const int* __restrict__ t2i, const float* __restrict__ t2v,
    const int* __restrict__ offs, int* __restrict__ fill,
    int* __restrict__ atok, float* __restrict__ agate) {
    const int n = blockIdx.x * 256 + threadIdx.x;
#pragma unroll
    for (int k = 0; k < 2; ++k) {
        int e = t2i[2 * n + k];
        int pos = offs[e] + atomicAdd(&fill[e], 1);
        atok[pos] = n;
        agate[pos] = t2v[2 * n + k];
    }
}

// ---------------------------------------------------------------------------
// GEMM: C[M][NC] = A[M][KD] * B^T[NC][KD]   (both bf16, fp32 accum)
// MODE 0: expert L1  (A = gathered x, out = gelu*gate -> Hb)
// MODE 1: expert L2  (A = Hb, out = atomicAdd into Y[token])
// MODE 2: shared L1  (A = x, out = gelu -> Hb)
// MODE 3: shared L2  (A = Hs, out = Y[row] = gsh*acc, plain store)
template <int MODE>
__global__ __launch_bounds__(256) void gemm_tile(
    const unsigned short* __restrict__ A, const unsigned short* __restrict__ B,
    float* __restrict__ Y, unsigned short* __restrict__ Hb,
    const int* __restrict__ offs, const int* __restrict__ atok,
    const float* __restrict__ agate, const float* __restrict__ gsh) {
    constexpr int KD = (MODE == 0 || MODE == 2) ? DDIM : HDIM;
    constexpr int NC = (MODE == 0 || MODE == 2) ? HDIM : DDIM;
    const int e = blockIdx.z;
    int m0 = 0, mE = N_TOK;
    if (MODE <= 1) { m0 = offs[e]; mE = offs[e + 1] - m0; }
    const int tm = blockIdx.y;
    if (tm * 128 >= mE) return;
    const int n0 = blockIdx.x * 128;

    __shared__ __align__(16) unsigned short As[128 * 32];
    __shared__ __align__(16) unsigned short Bs[128 * 32];

    const int tid = threadIdx.x, lane = tid & 63;
    const int wid = tid >> 6, wm = wid >> 1, wn = wid & 1;

    // staging descriptors: 2 chunks of A + 2 of B per thread per K-step
    const unsigned short* srcA[2];
    const unsigned short* srcB[2];
    char* dstA[2];
    char* dstB[2];
#pragma unroll
    for (int it = 0; it < 2; ++it) {
        int c = tid + it * 256;
        int row = c >> 2, slot = c & 3;
        int ksw = (slot ^ ((row >> 1) & 3)) * 8;   // pre-swizzled global k-chunk
        int arow = tm * 128 + row;
        if (MODE == 0) {
            int ar = arow < mE ? arow : mE - 1;
            srcA[it] = A + (size_t)atok[m0 + ar] * DDIM + ksw;
        } else if (MODE == 1) {
            int ar = arow < mE ? arow : mE - 1;
            srcA[it] = A + (size_t)(m0 + ar) * HDIM + ksw;
        } else {
            srcA[it] = A + (size_t)arow * KD + ksw;
        }
        srcB[it] = B + (MODE <= 1 ? (size_t)e * KD * NC : (size_t)0)
                     + (size_t)(n0 + row) * KD + ksw;
        dstA[it] = (char*)As + c * 16;
        dstB[it] = (char*)Bs + c * 16;
    }

    f32x4 acc[4][4] = {};

#pragma unroll 1
    for (int kk = 0; kk < KD; kk += 32) {
        if (kk) __syncthreads();
        gld16(dstA[0], srcA[0] + kk);
        gld16(dstA[1], srcA[1] + kk);
        gld16(dstB[0], srcB[0] + kk);
        gld16(dstB[1], srcB[1] + kk);
        __syncthreads();
        bf16x8 av[4], bv[4];
#pragma unroll
        for (int mi = 0; mi < 4; ++mi) {
            int r = wm * 64 + mi * 16 + (lane & 15);
            int s = (lane >> 4) ^ ((r >> 1) & 3);
            av[mi] = *(const bf16x8*)((const char*)As + r * 64 + s * 16);
        }
#pragma unroll
        for (int ni = 0; ni < 4; ++ni) {
            int r = wn * 64 + ni * 16 + (lane & 15);
            int s = (lane >> 4) ^ ((r >> 1) & 3);
            bv[ni] = *(const bf16x8*)((const char*)Bs + r * 64 + s * 16);
        }
#pragma unroll
        for (int mi = 0; mi < 4; ++mi)
#pragma unroll
            for (int ni = 0; ni < 4; ++ni)
                acc[mi][ni] = __builtin_amdgcn_mfma_f32_16x16x32_bf16(
                    av[mi], bv[ni], acc[mi][ni], 0, 0, 0);
    }

    // epilogue: C/D layout col = lane&15, row = (lane>>4)*4 + reg
    const int col = lane & 15, r4 = (lane >> 4) * 4;
#pragma unroll
    for (int mi = 0; mi < 4; ++mi) {
#pragma unroll
        for (int r = 0; r < 4; ++r) {
            int grow = tm * 128 + wm * 64 + mi * 16 + r4 + r;
            if (MODE <= 1 && grow >= mE) continue;
            float gate = 1.0f; int tok = 0; float g3 = 0.0f;
            if (MODE == 0) gate = agate[m0 + grow];
            if (MODE == 1) tok = atok[m0 + grow];
            if (MODE == 3) g3 = gsh[grow];
#pragma unroll
            for (int ni = 0; ni < 4; ++ni) {
                int gcol = n0 + wn * 64 + ni * 16 + col;
                float v = acc[mi][ni][r];
                if (MODE == 0) {
                    Hb[(size_t)(m0 + grow) * HDIM + gcol] = f2bf(gelu_f(v) * gate);
                } else if (MODE == 1) {
                    unsafeAtomicAdd(&Y[(size_t)tok * DDIM + gcol], v);
                } else if (MODE == 2) {
                    Hb[(size_t)grow * HDIM + gcol] = f2bf(gelu_f(v));
                } else {
                    Y[(size_t)grow * DDIM + gcol] = g3 * v;
                }
            }
        }
    }
}

// ---------------------------------------------------------------------------
extern "C" void kernel_launch(void* const* d_in, const int* in_sizes, int n_in,
                              void* d_out, int out_size, void* d_ws, size_t ws_size,
                              hipStream_t stream) {
    const float* x   = (const float*)d_in[0];
    const float* Wr  = (const float*)d_in[1];
    const float* Wg  = (const float*)d_in[2];
    const float* W1  = (const float*)d_in[3];
    const float* W2  = (const float*)d_in[4];
    const float* W1s = (const float*)d_in[5];
    const float* W2s = (const float*)d_in[6];
    float* out = (float*)d_out;

    char* ws = (char*)d_ws;
    size_t off = 0;
    auto carve = [&](size_t bytes) { char* p = ws + off; off += (bytes + 255) & ~(size_t)255; return p; };
    unsigned short* xb    = (unsigned short*)carve((size_t)N_TOK * DDIM * 2);
    unsigned short* w1t   = (unsigned short*)carve((size_t)NEXP * DDIM * HDIM * 2);
    unsigned short* w2t   = (unsigned short*)carve((size_t)NEXP * HDIM * DDIM * 2);
    unsigned short* w1st  = (unsigned short*)carve((size_t)DDIM * FDIM * 2);
    unsigned short* w2st  = (unsigned short*)carve((size_t)FDIM * DDIM * 2);
    unsigned short* hb    = (unsigned short*)carve((size_t)NASSIGN * HDIM * 2);
    unsigned short* hs    = (unsigned short*)carve((size_t)N_TOK * FDIM * 2);
    float* gsh            = (float*)carve((size_t)N_TOK * 4);
    int* t2i              = (int*)carve((size_t)N_TOK * 2 * 4);
    float* t2v            = (float*)carve((size_t)N_TOK * 2 * 4);
    int* atok             = (int*)carve((size_t)NASSIGN * 4);
    float* agate          = (float*)carve((size_t)NASSIGN * 4);
    float* imp            = (float*)carve(256);
    int* offs             = (int*)carve(256);
    int* fill             = (int*)carve(256);
    if (ws_size < off) return;   // fail loudly (output stays invalid)

    float* out_tail = out + (size_t)N_TOK * DDIM;

    hipLaunchKernelGGL(zero_small, dim3(1), dim3(256), 0, stream, imp);
    hipLaunchKernelGGL(cast_x_kernel, dim3(N_TOK * DDIM / 8 / 256), dim3(256), 0, stream, x, xb);
    hipLaunchKernelGGL((transpose_cast<DDIM, HDIM>), dim3(HDIM / 64, DDIM / 64, NEXP), dim3(256), 0, stream, W1, w1t);
    hipLaunchKernelGGL((transpose_cast<HDIM, DDIM>), dim3(DDIM / 64, HDIM / 64, NEXP), dim3(256), 0, stream, W2, w2t);
    hipLaunchKernelGGL((transpose_cast<DDIM, FDIM>), dim3(FDIM / 64, DDIM / 64, 1), dim3(256), 0, stream, W1s, w1st);
    hipLaunchKernelGGL((transpose_cast<FDIM, DDIM>), dim3(DDIM / 64, FDIM / 64, 1), dim3(256), 0, stream, W2s, w2st);
    hipLaunchKernelGGL(router_kernel, dim3(N_TOK / 4), dim3(256), 0, stream, x, Wr, Wg, gsh, t2i, t2v, imp);
    hipLaunchKernelGGL(scan_finalize, dim3(1), dim3(256), 0, stream, t2i, imp, offs, fill, out_tail);
    hipLaunchKernelGGL(build_assign, dim3(N_TOK / 256), dim3(256), 0, stream, t2i, t2v, offs, fill, atok, agate);

    // shared expert first: L2s plain-stores y, then expert L2 atomically adds
    hipLaunchKernelGGL((gemm_tile<2>), dim3(HDIM / 128, N_TOK / 128, 1), dim3(256), 0, stream,
                       xb, w1st, out, hs, offs, atok, agate, gsh);
    hipLaunchKernelGGL((gemm_tile<3>), dim3(DDIM / 128, N_TOK / 128, 1), dim3(256), 0, stream,
                       hs, w2st, out, nullptr, offs, atok, agate, gsh);
    hipLaunchKernelGGL((gemm_tile<0>), dim3(HDIM / 128, N_TOK / 128, NEXP), dim3(256), 0, stream,
                       xb, w1t, nullptr, hb, offs, atok, agate, gsh);
    hipLaunchKernelGGL((gemm_tile<1>), dim3(DDIM / 128, N_TOK / 128, NEXP), dim3(256), 0, stream,
                       hb, w2t, out, nullptr, offs, atok, agate, gsh);
}

// Round 5
// 668.838 us; speedup vs baseline: 1.0253x; 1.0238x over previous
//
#include <hip/hip_runtime.h>
#include <hip/hip_bf16.h>

// ---------------------------------------------------------------------------
// MoE layer: router (softmax, top-2) + 16 experts (D=2048 -> H=1024 -> D) +
// shared expert (D -> F=1024 -> D), gate-weighted combine, aux stats.
// Strategy: top-2 sparse dispatch + bf16 MFMA GEMMs.
// R4: (a) T3 minimum 2-phase double-buffered K-loop (stage next while
//     computing current, 1 barrier per buffer instead of 2 per step);
//     (b) expert-L2 epilogue: plain bf16 contrib stores (aliased onto dead
//     w1t) + gather-combine kernel instead of 33.5M fp32 atomics.
// ---------------------------------------------------------------------------

#define N_TOK 8192
#define DDIM  2048
#define NEXP  16
#define HDIM  1024
#define FDIM  1024
#define NASSIGN (N_TOK * 2)

typedef __attribute__((ext_vector_type(8))) short bf16x8;
typedef __attribute__((ext_vector_type(4))) float f32x4;
typedef __attribute__((ext_vector_type(8))) unsigned short u16x8;
typedef __attribute__((ext_vector_type(4))) unsigned short u16x4;

__device__ inline unsigned short f2bf(float f) {
    unsigned int u = __builtin_bit_cast(unsigned int, f);
    u += 0x7FFFu + ((u >> 16) & 1u);           // RNE (finite inputs only)
    return (unsigned short)(u >> 16);
}

__device__ inline float bf2f(unsigned short h) {
    return __builtin_bit_cast(float, (unsigned int)h << 16);
}

__device__ inline float gelu_f(float v) {
    return 0.5f * v * (1.0f + erff(v * 0.7071067811865475f));
}

__device__ inline void gld16(void* lds, const void* g) {
    __builtin_amdgcn_global_load_lds(
        (const __attribute__((address_space(1))) unsigned int*)g,
        (__attribute__((address_space(3))) unsigned int*)lds, 16, 0, 0);
}

// ---------------------------------------------------------------------------
__global__ __launch_bounds__(256) void zero_small(float* imp) {
    if (threadIdx.x < NEXP) imp[threadIdx.x] = 0.0f;
}

// x fp32 -> bf16, 8 elems/thread
__global__ __launch_bounds__(256) void cast_x_kernel(const float* __restrict__ x,
                                                     unsigned short* __restrict__ xb) {
    size_t i = (size_t)blockIdx.x * 256 + threadIdx.x;   // group of 8
    const float4 a = ((const float4*)x)[i * 2];
    const float4 b = ((const float4*)x)[i * 2 + 1];
    u16x8 o;
    o[0] = f2bf(a.x); o[1] = f2bf(a.y); o[2] = f2bf(a.z); o[3] = f2bf(a.w);
    o[4] = f2bf(b.x); o[5] = f2bf(b.y); o[6] = f2bf(b.z); o[7] = f2bf(b.w);
    *(u16x8*)(xb + i * 8) = o;
}

// [R][C] fp32 -> [C][R] bf16, 64x64 LDS tiles, batched over blockIdx.z
template <int R, int C>
__global__ __launch_bounds__(256) void transpose_cast(const float* __restrict__ src,
                                                      unsigned short* __restrict__ dst) {
    __shared__ unsigned short t[64][66];
    const size_t zoff = (size_t)blockIdx.z * R * C;
    src += zoff; dst += zoff;
    const int r0 = blockIdx.y * 64, c0 = blockIdx.x * 64;
    const int tid = threadIdx.x;
    const int cr = tid >> 4;            // 0..15
    const int cc4 = (tid & 15) * 4;
#pragma unroll
    for (int it = 0; it < 4; ++it) {
        int row = cr + it * 16;
        const float4 v = *(const float4*)(src + (size_t)(r0 + row) * C + c0 + cc4);
        t[row][cc4 + 0] = f2bf(v.x); t[row][cc4 + 1] = f2bf(v.y);
        t[row][cc4 + 2] = f2bf(v.z); t[row][cc4 + 3] = f2bf(v.w);
    }
    __syncthreads();
#pragma unroll
    for (int it = 0; it < 4; ++it) {
        int cc = cr + it * 16;
        u16x4 o;
#pragma unroll
        for (int j = 0; j < 4; ++j) o[j] = t[cc4 + j][cc];
        *(u16x4*)(dst + (size_t)(c0 + cc) * R + r0 + cc4) = o;
    }
}

// ---------------------------------------------------------------------------
// Router: one wave per token. logits = x@Wr (16), gate = x@Wg; softmax; top-2.
__global__ __launch_bounds__(256) void router_kernel(
    const float* __restrict__ x, const float* __restrict__ Wr, const float* __restrict__ Wg,
    float* __restrict__ gsh, int* __restrict__ t2i, float* __restrict__ t2v,
    float* __restrict__ imp) {
    __shared__ float simp[NEXP];
    const int tid = threadIdx.x, lane = tid & 63, w = tid >> 6;
    if (tid < NEXP) simp[tid] = 0.0f;
    __syncthreads();
    const int n = blockIdx.x * 4 + w;
    const float* xr = x + (size_t)n * DDIM;
    float acc[NEXP];
#pragma unroll
    for (int e = 0; e < NEXP; ++e) acc[e] = 0.0f;
    float ag = 0.0f;
    for (int j = 0; j < DDIM / 64; ++j) {
        int d = lane + j * 64;
        float xv = xr[d];
        const float* wr = Wr + (size_t)d * NEXP;
#pragma unroll
        for (int e = 0; e < NEXP; ++e) acc[e] = fmaf(xv, wr[e], acc[e]);
        ag = fmaf(xv, Wg[d], ag);
    }
#pragma unroll
    for (int off = 32; off; off >>= 1) {
#pragma unroll
        for (int e = 0; e < NEXP; ++e) acc[e] += __shfl_xor(acc[e], off);
        ag += __shfl_xor(ag, off);
    }
    if (lane == 0) {
        float mx = acc[0];
#pragma unroll
        for (int e = 1; e < NEXP; ++e) mx = fmaxf(mx, acc[e]);
        float p[NEXP], s = 0.0f;
#pragma unroll
        for (int e = 0; e < NEXP; ++e) { p[e] = expf(acc[e] - mx); s += p[e]; }
        const float inv = 1.0f / s;
        int i1 = 0; float v1 = -1.0f;
#pragma unroll
        for (int e = 0; e < NEXP; ++e) {
            p[e] *= inv;
            if (p[e] > v1) { v1 = p[e]; i1 = e; }
        }
        int i2 = 0; float v2 = -1.0f;
#pragma unroll
        for (int e = 0; e < NEXP; ++e) {
            if (e != i1 && p[e] > v2) { v2 = p[e]; i2 = e; }
        }
        t2i[2 * n] = i1; t2i[2 * n + 1] = i2;
        t2v[2 * n] = v1; t2v[2 * n + 1] = v2;
        gsh[n] = 1.0f / (1.0f + expf(-ag));
#pragma unroll
        for (int e = 0; e < NEXP; ++e) atomicAdd(&simp[e], p[e]);
    }
    __syncthreads();
    if (tid < NEXP) unsafeAtomicAdd(&imp[tid], simp[tid]);
}

// Single block: histogram counts, exclusive scan -> offsets, aux outputs, fill=0
__global__ __launch_bounds__(256) void scan_finalize(
    const int* __restrict__ t2i, const float* __restrict__ imp,
    int* __restrict__ offs, int* __restrict__ fill, float* __restrict__ out_tail) {
    __shared__ int hist[NEXP];
    const int tid = threadIdx.x;
    if (tid < NEXP) hist[tid] = 0;
    __syncthreads();
    for (int i = tid; i < NASSIGN; i += 256) atomicAdd(&hist[t2i[i]], 1);
    __syncthreads();
    if (tid == 0) {
        int o = 0;
        for (int e = 0; e < NEXP; ++e) { offs[e] = o; o += hist[e]; }
        offs[NEXP] = o;
    }
    if (tid < NEXP) {
        fill[tid] = 0;
        out_tail[tid] = imp[tid] * (1.0f / (float)N_TOK);
        out_tail[NEXP + tid] = (float)hist[tid] / (float)NASSIGN;
    }
}

// also records t2pos: inverse map (token, k) -> assignment slot for combine
__global__ __launch_bounds__(256) void build_assign(
    const int* __restrict__ t2i, const float* __restrict__ t2v,
    const int* __restrict__ offs, int* __restrict__ fill,
    int* __restrict__ atok, float* __restrict__ agate, int* __restrict__ t2pos) {
    const int n = blockIdx.x * 256 + threadIdx.x;
#pragma unroll
    for (int k = 0; k < 2; ++k) {
        int e = t2i[2 * n + k];
        int pos = offs[e] + atomicAdd(&fill[e], 1);
        atok[pos] = n;
        agate[pos] = t2v[2 * n + k];
        t2pos[2 * n + k] = pos;
    }
}

// y[n][d] += contrib[p0][d] + contrib[p1][d]   (contrib bf16, gathered rows)
__global__ __launch_bounds__(256) void combine_kernel(
    const unsigned short* __restrict__ contrib, const int* __restrict__ t2pos,
    float* __restrict__ y) {
    const int gi = blockIdx.x * 256 + threadIdx.x;      // group of 8 floats
    const int n = gi >> 8;                              // DDIM/8 = 256 groups/row
    const int d8 = (gi & 255) * 8;
    const int p0 = t2pos[2 * n], p1 = t2pos[2 * n + 1];
    u16x8 a = *(const u16x8*)(contrib + (size_t)p0 * DDIM + d8);
    u16x8 b = *(const u16x8*)(contrib + (size_t)p1 * DDIM + d8);
    float* yr = y + (size_t)n * DDIM + d8;
    float4 y0 = *(float4*)yr;
    float4 y1 = *(float4*)(yr + 4);
    y0.x += bf2f(a[0]) + bf2f(b[0]);
    y0.y += bf2f(a[1]) + bf2f(b[1]);
    y0.z += bf2f(a[2]) + bf2f(b[2]);
    y0.w += bf2f(a[3]) + bf2f(b[3]);
    y1.x += bf2f(a[4]) + bf2f(b[4]);
    y1.y += bf2f(a[5]) + bf2f(b[5]);
    y1.z += bf2f(a[6]) + bf2f(b[6]);
    y1.w += bf2f(a[7]) + bf2f(b[7]);
    *(float4*)yr = y0;
    *(float4*)(yr + 4) = y1;
}

// ---------------------------------------------------------------------------
// GEMM: C[M][NC] = A[M][KD] * B^T[NC][KD]   (both bf16, fp32 accum)
// 2-phase double-buffered K-loop: stage(next) issued BEFORE compute(current),
// one __syncthreads per buffer (compiler's barrier drain covers vmcnt).
// MODE 0: expert L1  (A = gathered x, out = gelu*gate -> Hb bf16)
// MODE 1: expert L2  (A = Hb, out = bf16 contrib row store -> Hb param)
// MODE 2: shared L1  (A = x, out = gelu -> Hb bf16)
// MODE 3: shared L2  (A = Hs, out = Y[row] = gsh*acc, plain fp32 store)
template <int MODE>
__global__ __launch_bounds__(256) void gemm_tile(
    const unsigned short* __restrict__ A, const unsigned short* __restrict__ B,
    float* __restrict__ Y, unsigned short* __restrict__ Hb,
    const int* __restrict__ offs, const int* __restrict__ atok,
    const float* __restrict__ agate, const float* __restrict__ gsh) {
    constexpr int KD = (MODE == 0 || MODE == 2) ? DDIM : HDIM;
    constexpr int NC = (MODE == 0 || MODE == 2) ? HDIM : DDIM;
    const int e = blockIdx.z;
    int m0 = 0, mE = N_TOK;
    if (MODE <= 1) { m0 = offs[e]; mE = offs[e + 1] - m0; }
    const int tm = blockIdx.y;
    if (tm * 128 >= mE) return;
    const int n0 = blockIdx.x * 128;

    __shared__ __align__(16) unsigned short As[2][128 * 32];
    __shared__ __align__(16) unsigned short Bs[2][128 * 32];

    const int tid = threadIdx.x, lane = tid & 63;
    const int wid = tid >> 6, wm = wid >> 1, wn = wid & 1;

    // staging descriptors: 2 chunks of A + 2 of B per thread per K-step
    const unsigned short* sA[2];
    const unsigned short* sB[2];
    int dOff[2];
#pragma unroll
    for (int it = 0; it < 2; ++it) {
        int c = tid + it * 256;
        int row = c >> 2, slot = c & 3;
        int ksw = (slot ^ ((row >> 1) & 3)) * 8;   // pre-swizzled global k-chunk
        int arow = tm * 128 + row;
        if (MODE == 0) {
            int ar = arow < mE ? arow : mE - 1;
            sA[it] = A + (size_t)atok[m0 + ar] * DDIM + ksw;
        } else if (MODE == 1) {
            int ar = arow < mE ? arow : mE - 1;
            sA[it] = A + (size_t)(m0 + ar) * HDIM + ksw;
        } else {
            sA[it] = A + (size_t)arow * KD + ksw;
        }
        sB[it] = B + (MODE <= 1 ? (size_t)e * KD * NC : (size_t)0)
                   + (size_t)(n0 + row) * KD + ksw;
        dOff[it] = c * 16;
    }

    f32x4 acc[4][4] = {};

    auto stage = [&](int b, int kk) {
        gld16((char*)As[b] + dOff[0], sA[0] + kk);
        gld16((char*)As[b] + dOff[1], sA[1] + kk);
        gld16((char*)Bs[b] + dOff[0], sB[0] + kk);
        gld16((char*)Bs[b] + dOff[1], sB[1] + kk);
    };
    auto compute = [&](int b) {
        bf16x8 av[4], bv[4];
#pragma unroll
        for (int mi = 0; mi < 4; ++mi) {
            int r = wm * 64 + mi * 16 + (lane & 15);
            int s = (lane >> 4) ^ ((r >> 1) & 3);
            av[mi] = *(const bf16x8*)((const char*)As[b] + r * 64 + s * 16);
        }
#pragma unroll
        for (int ni = 0; ni < 4; ++ni) {
            int r = wn * 64 + ni * 16 + (lane & 15);
            int s = (lane >> 4) ^ ((r >> 1) & 3);
            bv[ni] = *(const bf16x8*)((const char*)Bs[b] + r * 64 + s * 16);
        }
#pragma unroll
        for (int mi = 0; mi < 4; ++mi)
#pragma unroll
            for (int ni = 0; ni < 4; ++ni)
                acc[mi][ni] = __builtin_amdgcn_mfma_f32_16x16x32_bf16(
                    av[mi], bv[ni], acc[mi][ni], 0, 0, 0);
    };

    // prologue: fill buffer 0
    stage(0, 0);
    __syncthreads();

#pragma unroll 1
    for (int kk = 0; kk < KD; kk += 64) {
        stage(1, kk + 32);          // kk+32 < KD always (KD % 64 == 0)
        compute(0);
        __syncthreads();            // drains vmcnt (stage) + all reads of buf0 done
        if (kk + 64 < KD) stage(0, kk + 64);
        compute(1);
        __syncthreads();
    }

    // epilogue: C/D layout col = lane&15, row = (lane>>4)*4 + reg
    const int col = lane & 15, r4 = (lane >> 4) * 4;
#pragma unroll
    for (int mi = 0; mi < 4; ++mi) {
#pragma unroll
        for (int r = 0; r < 4; ++r) {
            int grow = tm * 128 + wm * 64 + mi * 16 + r4 + r;
            if (MODE <= 1 && grow >= mE) continue;
            float gate = 1.0f; float g3 = 0.0f;
            if (MODE == 0) gate = agate[m0 + grow];
            if (MODE == 3) g3 = gsh[grow];
#pragma unroll
            for (int ni = 0; ni < 4; ++ni) {
                int gcol = n0 + wn * 64 + ni * 16 + col;
                float v = acc[mi][ni][r];
                if (MODE == 0) {
                    Hb[(size_t)(m0 + grow) * HDIM + gcol] = f2bf(gelu_f(v) * gate);
                } else if (MODE == 1) {
                    Hb[(size_t)(m0 + grow) * DDIM + gcol] = f2bf(v);   // contrib
                } else if (MODE == 2) {
                    Hb[(size_t)grow * HDIM + gcol] = f2bf(gelu_f(v));
                } else {
                    Y[(size_t)grow * DDIM + gcol] = g3 * v;
                }
            }
        }
    }
}

// ---------------------------------------------------------------------------
extern "C" void kernel_launch(void* const* d_in, const int* in_sizes, int n_in,
                              void* d_out, int out_size, void* d_ws, size_t ws_size,
                              hipStream_t stream) {
    const float* x   = (const float*)d_in[0];
    const float* Wr  = (const float*)d_in[1];
    const float* Wg  = (const float*)d_in[2];
    const float* W1  = (const float*)d_in[3];
    const float* W2  = (const float*)d_in[4];
    const float* W1s = (const float*)d_in[5];
    const float* W2s = (const float*)d_in[6];
    float* out = (float*)d_out;

    char* ws = (char*)d_ws;
    size_t off = 0;
    auto carve = [&](size_t bytes) { char* p = ws + off; off += (bytes + 255) & ~(size_t)255; return p; };
    unsigned short* xb    = (unsigned short*)carve((size_t)N_TOK * DDIM * 2);
    unsigned short* w1t   = (unsigned short*)carve((size_t)NEXP * DDIM * HDIM * 2);
    unsigned short* w2t   = (unsigned short*)carve((size_t)NEXP * HDIM * DDIM * 2);
    unsigned short* w1st  = (unsigned short*)carve((size_t)DDIM * FDIM * 2);
    unsigned short* w2st  = (unsigned short*)carve((size_t)FDIM * DDIM * 2);
    unsigned short* hb    = (unsigned short*)carve((size_t)NASSIGN * HDIM * 2);
    unsigned short* hs    = (unsigned short*)carve((size_t)N_TOK * FDIM * 2);
    float* gsh            = (float*)carve((size_t)N_TOK * 4);
    int* t2i              = (int*)carve((size_t)N_TOK * 2 * 4);
    float* t2v            = (float*)carve((size_t)N_TOK * 2 * 4);
    int* atok             = (int*)carve((size_t)NASSIGN * 4);
    float* agate          = (float*)carve((size_t)NASSIGN * 4);
    int* t2pos            = (int*)carve((size_t)NASSIGN * 4);
    float* imp            = (float*)carve(256);
    int* offs             = (int*)carve(256);
    int* fill             = (int*)carve(256);
    if (ws_size < off) return;   // fail loudly (output stays invalid)

    // contrib (bf16, NASSIGN x DDIM = 64 MiB) aliases w1t (same size), which is
    // dead after gemm_tile<0> reads it; stream order serializes the reuse.
    unsigned short* contrib = w1t;

    float* out_tail = out + (size_t)N_TOK * DDIM;

    hipLaunchKernelGGL(zero_small, dim3(1), dim3(256), 0, stream, imp);
    hipLaunchKernelGGL(cast_x_kernel, dim3(N_TOK * DDIM / 8 / 256), dim3(256), 0, stream, x, xb);
    hipLaunchKernelGGL((transpose_cast<DDIM, HDIM>), dim3(HDIM / 64, DDIM / 64, NEXP), dim3(256), 0, stream, W1, w1t);
    hipLaunchKernelGGL((transpose_cast<HDIM, DDIM>), dim3(DDIM / 64, HDIM / 64, NEXP), dim3(256), 0, stream, W2, w2t);
    hipLaunchKernelGGL((transpose_cast<DDIM, FDIM>), dim3(FDIM / 64, DDIM / 64, 1), dim3(256), 0, stream, W1s, w1st);
    hipLaunchKernelGGL((transpose_cast<FDIM, DDIM>), dim3(DDIM / 64, FDIM / 64, 1), dim3(256), 0, stream, W2s, w2st);
    hipLaunchKernelGGL(router_kernel, dim3(N_TOK / 4), dim3(256), 0, stream, x, Wr, Wg, gsh, t2i, t2v, imp);
    hipLaunchKernelGGL(scan_finalize, dim3(1), dim3(256), 0, stream, t2i, imp, offs, fill, out_tail);
    hipLaunchKernelGGL(build_assign, dim3(N_TOK / 256), dim3(256), 0, stream, t2i, t2v, offs, fill, atok, agate, t2pos);

    // shared expert: L1 -> hs, L2 plain-stores gsh-scaled y into out
    hipLaunchKernelGGL((gemm_tile<2>), dim3(HDIM / 128, N_TOK / 128, 1), dim3(256), 0, stream,
                       xb, w1st, out, hs, offs, atok, agate, gsh);
    hipLaunchKernelGGL((gemm_tile<3>), dim3(DDIM / 128, N_TOK / 128, 1), dim3(256), 0, stream,
                       hs, w2st, out, nullptr, offs, atok, agate, gsh);
    // expert path: L1 -> hb (reads w1t), L2 -> contrib rows (overwrites w1t)
    hipLaunchKernelGGL((gemm_tile<0>), dim3(HDIM / 128, N_TOK / 128, NEXP), dim3(256), 0, stream,
                       xb, w1t, nullptr, hb, offs, atok, agate, gsh);
    hipLaunchKernelGGL((gemm_tile<1>), dim3(DDIM / 128, N_TOK / 128, NEXP), dim3(256), 0, stream,
                       hb, w2t, nullptr, contrib, offs, atok, agate, gsh);
    // y[n] += contrib[pos0] + contrib[pos1]
    hipLaunchKernelGGL(combine_kernel, dim3(N_TOK * DDIM / 8 / 256), dim3(256), 0, stream,
                       contrib, t2pos, out);
}